// Round 9
// baseline (959.379 us; speedup 1.0000x reference)
//
#include <hip/hip_runtime.h>
#include <hip/hip_bf16.h>
#include <hip/hip_fp16.h>
#include <math.h>

#define TT 256
#define BB 64
#define HH 1024
#define VV 512
#define NEGV -10000.0f
#define BOSI 1
#define CI 128          // i-chunk per block
#define NK 4            // chunks per batch element
#define NW 44           // payload words per chunk (43 data + 1 cm)
#define PSTRIDE 64      // u64 stride per chunk slot

// ws layout:
//   [0, 1M)        : ET float32 [VV][VV]   (ET[j][i] = exp(trans[i][j]))
//   [1M, 17M)      : feats bf16 [BB][TT][VV]
//   [17M, 17M+256K): payload u64 [BB][2 slots][NK][PSTRIDE]
//   [18M, 50M)     : Abf bf16 [T*B][H]
//   [50M, 51M)     : Wbf bf16 [V][H]

typedef __attribute__((ext_vector_type(8))) short frag;
typedef __attribute__((ext_vector_type(4))) float f4;

#define GLL16(g, l) __builtin_amdgcn_global_load_lds( \
    (const __attribute__((address_space(1))) void*)(g), \
    (__attribute__((address_space(3))) void*)(l), 16, 0, 0)

// ---------------- ET[j][i] = exp(trans[i][j]) fp32, LDS-tiled transpose ----
__global__ __launch_bounds__(256)
void k_expT(const float* __restrict__ trans, float* __restrict__ ET) {
    __shared__ float tile[32][33];
    int bi = blockIdx.x, bj = blockIdx.y;
    int tx = threadIdx.x & 31;
    int ty = threadIdx.x >> 5;
#pragma unroll
    for (int k = 0; k < 4; ++k) {
        int i = bi * 32 + ty + k * 8;
        tile[ty + k * 8][tx] = expf(trans[i * VV + bj * 32 + tx]);
    }
    __syncthreads();
#pragma unroll
    for (int k = 0; k < 4; ++k) {
        int j = bj * 32 + ty + k * 8;
        ET[j * VV + bi * 32 + tx] = tile[tx][ty + k * 8];
    }
}

// ---------------- zero payload tags ----------------
__global__ __launch_bounds__(256)
void k_zero(unsigned long long* __restrict__ pay) {
    pay[blockIdx.x * 256 + threadIdx.x] = 0ull;   // grid 128 -> 32768 words
}

// ---------------- fp32 -> bf16 cast ----------------
__global__ __launch_bounds__(256)
void k_cast(const float* __restrict__ src, __hip_bfloat16* __restrict__ dst) {
    int i = blockIdx.x * 256 + threadIdx.x;
    float4 v = ((const float4*)src)[i];
    __hip_bfloat16 o[4];
    o[0] = __float2bfloat16(v.x); o[1] = __float2bfloat16(v.y);
    o[2] = __float2bfloat16(v.z); o[3] = __float2bfloat16(v.w);
    *(uint2*)&dst[i * 4] = *(uint2*)o;
}

// ---------------- MFMA feats GEMM (verified in rounds 7-8) ------------------
__global__ __launch_bounds__(256)
void k_feats(const __hip_bfloat16* __restrict__ Abf, const __hip_bfloat16* __restrict__ Wbf,
             const float* __restrict__ bias, __hip_bfloat16* __restrict__ feats) {
    __shared__ short As[128 * 32];
    __shared__ short Ws[128 * 32];
    int tid = threadIdx.x;
    int wave = tid >> 6, lane = tid & 63;
    int quad = lane >> 4, l16 = lane & 15;
    int wm = wave & 1, wn = wave >> 1;
    int row0 = blockIdx.x * 128;
    int col0 = blockIdx.y * 128;
    const short* Ag = (const short*)Abf;
    const short* Wg = (const short*)Wbf;

    f4 acc[4][4];
#pragma unroll
    for (int mt = 0; mt < 4; ++mt)
#pragma unroll
        for (int nt = 0; nt < 4; ++nt)
            acc[mt][nt] = (f4){0.f, 0.f, 0.f, 0.f};

    for (int kt = 0; kt < HH; kt += 32) {
#pragma unroll
        for (int s = 0; s < 2; ++s) {
            int idx = wave * 128 + s * 64 + lane;
            int r = idx >> 2, q = idx & 3;
            GLL16(Ag + (size_t)(row0 + r) * HH + kt + q * 8,
                  &As[(wave * 128 + s * 64) * 8]);
            GLL16(Wg + (size_t)(col0 + r) * HH + kt + q * 8,
                  &Ws[(wave * 128 + s * 64) * 8]);
        }
        __syncthreads();
        frag a[4], b[4];
#pragma unroll
        for (int mt = 0; mt < 4; ++mt)
            a[mt] = *(const frag*)&As[(wm * 64 + mt * 16 + l16) * 32 + quad * 8];
#pragma unroll
        for (int nt = 0; nt < 4; ++nt)
            b[nt] = *(const frag*)&Ws[(wn * 64 + nt * 16 + l16) * 32 + quad * 8];
#pragma unroll
        for (int mt = 0; mt < 4; ++mt)
#pragma unroll
            for (int nt = 0; nt < 4; ++nt)
                acc[mt][nt] = __builtin_amdgcn_mfma_f32_16x16x32_bf16(
                    a[mt], b[nt], acc[mt][nt], 0, 0, 0);
        __syncthreads();
    }

    float bv[4];
#pragma unroll
    for (int nt = 0; nt < 4; ++nt)
        bv[nt] = bias[col0 + wn * 64 + nt * 16 + l16];
#pragma unroll
    for (int mt = 0; mt < 4; ++mt) {
#pragma unroll
        for (int nt = 0; nt < 4; ++nt) {
#pragma unroll
            for (int r = 0; r < 4; ++r) {
                int row = row0 + wm * 64 + mt * 16 + quad * 4 + r;   // = t*64+b
                int col = col0 + wn * 64 + nt * 16 + l16;
                int t = row >> 6, bb = row & 63;
                feats[((size_t)bb * TT + t) * VV + col] =
                    __float2bfloat16(acc[mt][nt][r] + bv[nt]);
            }
        }
    }
}

// ------- i-split scan: 512 thr, AGPR-resident eta, 2 chains per block -------
__global__ __launch_bounds__(512, 2)
void k_scan(const float* __restrict__ ETg,
            const __hip_bfloat16* __restrict__ feats,
            const int* __restrict__ lengths,
            unsigned long long* __restrict__ pay,
            float* __restrict__ out) {
    __shared__ float spf[16 * 36];   // p fp32: row js (32 j), pad 36
    __shared__ float spart[16 * CI]; // 16 js-partials x 128 i
    __shared__ float sLz[CI];
    __shared__ float sm[NK];
    __shared__ float sred[2];
    __shared__ float sfin[4];

    int tid = threadIdx.x;
    int g   = blockIdx.x & 31;       // chain-pair group; peers {g,32+g,64+g,96+g} same XCD (%8)
    int kc  = blockIdx.x >> 5;       // i-chunk 0..3
    int b0 = 2 * g, b1 = 2 * g + 1;
    int lane = tid & 63, wid = tid >> 6;
    int len0 = lengths[b0], len1 = lengths[b1];
    int js = tid >> 5;               // j-slice 0..15 (32 j each)
    int ig = tid & 31;
    int i0 = ig * 4;                 // 4 i's per thread

#define PSLOT(bq, s, c) (pay + ((size_t)(bq) * 2 * NK + (size_t)(s) * NK + (c)) * PSTRIDE)

    // ---- ET sub-block -> 128 regs (AGPR-backed): rows j=js*32..+32, 4 cols --
    float eta[128];
    {
        const float* base = ETg + (size_t)(js * 32) * VV + kc * CI + i0;
#pragma unroll
        for (int jj = 0; jj < 32; ++jj) {
            float4 v = *(const float4*)(base + jj * VV);
            eta[jj * 4 + 0] = v.x; eta[jj * 4 + 1] = v.y;
            eta[jj * 4 + 2] = v.z; eta[jj * 4 + 3] = v.w;
        }
    }

    // ---- init publish round 1 -> slot 1, both chains ----
    if (tid < NW) {
        float cm0 = (kc == 0) ? 0.f : NEGV;
        unsigned long long v;
        if (tid == NW - 1) {
            v = (1ull << 48) | (unsigned long long)__float_as_uint(cm0);
        } else {
            unsigned long long h[3] = {0ull, 0ull, 0ull};
#pragma unroll
            for (int r = 0; r < 3; ++r) {
                int idx = 3 * tid + r;
                if (idx < CI) {
                    int gi = kc * CI + idx;
                    float z = (gi == BOSI) ? 0.f : NEGV;
                    h[r] = (unsigned long long)__half_as_ushort(__float2half(expf(z - cm0)));
                }
            }
            v = (1ull << 48) | (h[2] << 32) | (h[1] << 16) | h[0];
        }
        __hip_atomic_store(&PSLOT(b0, 1, kc)[tid], v, __ATOMIC_RELAXED, __HIP_MEMORY_SCOPE_AGENT);
        __hip_atomic_store(&PSLOT(b1, 1, kc)[tid], v, __ATOMIC_RELAXED, __HIP_MEMORY_SCOPE_AGENT);
    }

    const __hip_bfloat16* fb0 = feats + (size_t)b0 * TT * VV;
    const __hip_bfloat16* fb1 = feats + (size_t)b1 * TT * VV;
    int pc = (tid >= 132) ? 3 : (tid >= 88) ? 2 : (tid >= 44) ? 1 : 0;
    int pw = tid - pc * 44;

    auto phase = [&](int bq, const __hip_bfloat16* fb, int t) {
        float ft = 0.f;
        if (tid < CI) ft = __bfloat162float(fb[(size_t)t * VV + kc * CI + tid]);

        // poll all 4 chunks' payloads (tid<176), unpack into LDS
        if (tid < NK * NW) {
            const unsigned long long* wp = &PSLOT(bq, (t + 1) & 1, pc)[pw];
            unsigned tgt = (unsigned)(t + 1);
            unsigned long long v;
            do {
                v = __hip_atomic_load(wp, __ATOMIC_RELAXED, __HIP_MEMORY_SCOPE_AGENT);
            } while ((unsigned)(v >> 48) < tgt);
            if (pw == NW - 1) {
                sm[pc] = __uint_as_float((unsigned)v);
            } else {
#pragma unroll
                for (int r = 0; r < 3; ++r) {
                    int idx = 3 * pw + r;
                    if (idx < CI) {
                        int j = pc * CI + idx;
                        spf[36 * (j >> 5) + (j & 31)] =
                            __half2float(__ushort_as_half((unsigned short)(v >> (16 * r))));
                    }
                }
            }
        }
        __syncthreads();   // B1

        float M = fmaxf(fmaxf(sm[0], sm[1]), fmaxf(sm[2], sm[3]));
        float wloc = expf(sm[js >> 2] - M);   // my js's source chunk (4 js per chunk)

        // matvec from registers: my 32 j's are exactly spf row js
        float a0 = 0.f, a1 = 0.f, a2 = 0.f, a3 = 0.f;
#pragma unroll
        for (int j4 = 0; j4 < 8; ++j4) {
            float4 pv = *(const float4*)&spf[36 * js + j4 * 4];
            float pj[4] = {pv.x, pv.y, pv.z, pv.w};
#pragma unroll
            for (int u = 0; u < 4; ++u) {
                int jj = j4 * 4 + u;
                float pq = pj[u];
                a0 = fmaf(eta[jj * 4 + 0], pq, a0);
                a1 = fmaf(eta[jj * 4 + 1], pq, a1);
                a2 = fmaf(eta[jj * 4 + 2], pq, a2);
                a3 = fmaf(eta[jj * 4 + 3], pq, a3);
            }
        }
        *(float4*)&spart[js * CI + i0] = make_float4(a0 * wloc, a1 * wloc, a2 * wloc, a3 * wloc);
        __syncthreads();   // B2

        // reduce 16 partials, z_new, chunk max
        if (tid < CI) {
            float s = 0.f;
#pragma unroll
            for (int q = 0; q < 16; ++q) s += spart[q * CI + tid];
            float zn = M + logf(s) + ft;
            sLz[tid] = zn;
            float cmv = zn;
#pragma unroll
            for (int off = 32; off > 0; off >>= 1)
                cmv = fmaxf(cmv, __shfl_xor(cmv, off, 64));
            if (lane == 0) sred[wid] = cmv;
        }
        __syncthreads();   // B3

        // pack + publish round t+2 -> slot t&1
        if (tid < NW) {
            float cm = fmaxf(sred[0], sred[1]);
            unsigned long long tg = (unsigned long long)(unsigned)(t + 2) << 48;
            unsigned long long v;
            if (tid == NW - 1) {
                v = tg | (unsigned long long)__float_as_uint(cm);
            } else {
                unsigned long long h[3] = {0ull, 0ull, 0ull};
#pragma unroll
                for (int r = 0; r < 3; ++r) {
                    int idx = 3 * tid + r;
                    if (idx < CI)
                        h[r] = (unsigned long long)__half_as_ushort(
                                   __float2half(expf(sLz[idx] - cm)));
                }
                v = tg | (h[2] << 32) | (h[1] << 16) | h[0];
            }
            __hip_atomic_store(&PSLOT(bq, t & 1, kc)[tid], v, __ATOMIC_RELAXED, __HIP_MEMORY_SCOPE_AGENT);
        }
    };

    int maxlen = max(len0, len1);
    for (int t = 0; t < maxlen; ++t) {
        if (t < len0) phase(b0, fb0, t);
        if (t < len1) phase(b1, fb1, t);
    }

    // ---- final LSE over all 512 states (kc==0 block), both chains ----
    if (kc == 0) {
#pragma unroll
        for (int c = 0; c < 2; ++c) {
            int bq = (c == 0) ? b0 : b1;
            int len = (c == 0) ? len0 : len1;
            if (tid < NK * NW) {
                const unsigned long long* wp = &PSLOT(bq, (len + 1) & 1, pc)[pw];
                unsigned tgt = (unsigned)(len + 1);
                unsigned long long v;
                do {
                    v = __hip_atomic_load(wp, __ATOMIC_RELAXED, __HIP_MEMORY_SCOPE_AGENT);
                } while ((unsigned)(v >> 48) < tgt);
                if (pw == NW - 1) {
                    sm[pc] = __uint_as_float((unsigned)v);
                } else {
#pragma unroll
                    for (int r = 0; r < 3; ++r) {
                        int idx = 3 * pw + r;
                        if (idx < CI) {
                            int j = pc * CI + idx;
                            spf[36 * (j >> 5) + (j & 31)] =
                                __half2float(__ushort_as_half((unsigned short)(v >> (16 * r))));
                        }
                    }
                }
            }
            __syncthreads();
            float M = fmaxf(fmaxf(sm[0], sm[1]), fmaxf(sm[2], sm[3]));
            if (tid < 256) {
                int j0 = 2 * tid;
                float w0 = expf(sm[j0 >> 7] - M);
                float v0 = spf[36 * (j0 >> 5) + (j0 & 31)];
                float v1 = spf[36 * ((j0 + 1) >> 5) + ((j0 + 1) & 31)];
                float s = (v0 + v1) * w0;
#pragma unroll
                for (int off = 32; off > 0; off >>= 1)
                    s += __shfl_xor(s, off, 64);
                if (lane == 0) sfin[wid] = s;
            }
            __syncthreads();
            if (tid == 0)
                out[bq] = M + logf(sfin[0] + sfin[1] + sfin[2] + sfin[3]);
            __syncthreads();   // protect sm/spf/sfin before chain 2 reuses
        }
    }
#undef PSLOT
}

extern "C" void kernel_launch(void* const* d_in, const int* in_sizes, int n_in,
                              void* d_out, int out_size, void* d_ws, size_t ws_size,
                              hipStream_t stream) {
    const float* enc     = (const float*)d_in[0];  // [T,B,H]
    const int*   lengths = (const int*)d_in[1];    // [B]
    const float* W       = (const float*)d_in[2];  // [V,H]
    const float* bias    = (const float*)d_in[3];  // [V]
    const float* trans   = (const float*)d_in[4];  // [V,V]
    float* out = (float*)d_out;

    char* ws = (char*)d_ws;
    float*          ETg   = (float*)ws;
    __hip_bfloat16* feats = (__hip_bfloat16*)(ws + (1 << 20));
    unsigned long long* pay = (unsigned long long*)(ws + (17 << 20));
    __hip_bfloat16* Abf   = (__hip_bfloat16*)(ws + (18 << 20));
    __hip_bfloat16* Wbf   = (__hip_bfloat16*)(ws + (50 << 20));

    hipLaunchKernelGGL(k_zero, dim3(128), dim3(256), 0, stream, pay);
    hipLaunchKernelGGL(k_expT, dim3(16, 16), dim3(256), 0, stream, trans, ETg);
    hipLaunchKernelGGL(k_cast, dim3(16384), dim3(256), 0, stream, enc, Abf);
    hipLaunchKernelGGL(k_cast, dim3(512), dim3(256), 0, stream, W, Wbf);
    hipLaunchKernelGGL(k_feats, dim3(16384 / 128, VV / 128), dim3(256), 0, stream,
                       Abf, Wbf, bias, feats);
    hipLaunchKernelGGL(k_scan, dim3(NK * 32), dim3(512), 0, stream,
                       ETg, feats, lengths, pay, out);
}

// Round 10
// 548.238 us; speedup vs baseline: 1.7499x; 1.7499x over previous
//
#include <hip/hip_runtime.h>
#include <hip/hip_bf16.h>
#include <hip/hip_fp16.h>
#include <math.h>

#define TT 256
#define BB 64
#define HH 1024
#define VV 512
#define NEGV -10000.0f
#define BOSI 1
#define CI 128          // i-chunk per block
#define NK 4            // chunks per batch element
#define PSTRIDE 64      // u64 words per chunk slot (64 words = 128 states)

// ws layout:
//   [0, 1M)        : ET float32 [VV][VV]   (ET[j][i] = exp(trans[i][j]))
//   [1M, 17M)      : feats bf16 [BB][TT][VV]
//   [17M, 17M+256K): payload u64 [BB][2 slots][NK][PSTRIDE]
//     word w: [63:48]=tag, [47:32]=cm bf16, [31:16]=p(2w+1) f16, [15:0]=p(2w) f16
//   [18M, 50M)     : Abf bf16 [T*B][H]
//   [50M, 51M)     : Wbf bf16 [V][H]

typedef __attribute__((ext_vector_type(8))) short frag;
typedef __attribute__((ext_vector_type(4))) float f4;
typedef __attribute__((ext_vector_type(2))) _Float16 h2;

#define GLL16(g, l) __builtin_amdgcn_global_load_lds( \
    (const __attribute__((address_space(1))) void*)(g), \
    (__attribute__((address_space(3))) void*)(l), 16, 0, 0)

__device__ __forceinline__ unsigned short f16b(float x) {
    return __half_as_ushort(__float2half(x));
}
__device__ __forceinline__ float f16f(unsigned int bits) {
    return __half2float(__ushort_as_half((unsigned short)(bits & 0xFFFFu)));
}

// ---------------- ET[j][i] = exp(trans[i][j]) fp32, LDS-tiled transpose ----
__global__ __launch_bounds__(256)
void k_expT(const float* __restrict__ trans, float* __restrict__ ET) {
    __shared__ float tile[32][33];
    int bi = blockIdx.x, bj = blockIdx.y;
    int tx = threadIdx.x & 31;
    int ty = threadIdx.x >> 5;
#pragma unroll
    for (int k = 0; k < 4; ++k) {
        int i = bi * 32 + ty + k * 8;
        tile[ty + k * 8][tx] = expf(trans[i * VV + bj * 32 + tx]);
    }
    __syncthreads();
#pragma unroll
    for (int k = 0; k < 4; ++k) {
        int j = bj * 32 + ty + k * 8;
        ET[j * VV + bi * 32 + tx] = tile[tx][ty + k * 8];
    }
}

// ---------------- zero payload tags ----------------
__global__ __launch_bounds__(256)
void k_zero(unsigned long long* __restrict__ pay) {
    pay[blockIdx.x * 256 + threadIdx.x] = 0ull;   // grid 128 -> 32768 words
}

// ---------------- fp32 -> bf16 cast ----------------
__global__ __launch_bounds__(256)
void k_cast(const float* __restrict__ src, __hip_bfloat16* __restrict__ dst) {
    int i = blockIdx.x * 256 + threadIdx.x;
    float4 v = ((const float4*)src)[i];
    __hip_bfloat16 o[4];
    o[0] = __float2bfloat16(v.x); o[1] = __float2bfloat16(v.y);
    o[2] = __float2bfloat16(v.z); o[3] = __float2bfloat16(v.w);
    *(uint2*)&dst[i * 4] = *(uint2*)o;
}

// ---------------- MFMA feats GEMM (verified rounds 7-9) ---------------------
__global__ __launch_bounds__(256)
void k_feats(const __hip_bfloat16* __restrict__ Abf, const __hip_bfloat16* __restrict__ Wbf,
             const float* __restrict__ bias, __hip_bfloat16* __restrict__ feats) {
    __shared__ short As[128 * 32];
    __shared__ short Ws[128 * 32];
    int tid = threadIdx.x;
    int wave = tid >> 6, lane = tid & 63;
    int quad = lane >> 4, l16 = lane & 15;
    int wm = wave & 1, wn = wave >> 1;
    int row0 = blockIdx.x * 128;
    int col0 = blockIdx.y * 128;
    const short* Ag = (const short*)Abf;
    const short* Wg = (const short*)Wbf;

    f4 acc[4][4];
#pragma unroll
    for (int mt = 0; mt < 4; ++mt)
#pragma unroll
        for (int nt = 0; nt < 4; ++nt)
            acc[mt][nt] = (f4){0.f, 0.f, 0.f, 0.f};

    for (int kt = 0; kt < HH; kt += 32) {
#pragma unroll
        for (int s = 0; s < 2; ++s) {
            int idx = wave * 128 + s * 64 + lane;
            int r = idx >> 2, q = idx & 3;
            GLL16(Ag + (size_t)(row0 + r) * HH + kt + q * 8,
                  &As[(wave * 128 + s * 64) * 8]);
            GLL16(Wg + (size_t)(col0 + r) * HH + kt + q * 8,
                  &Ws[(wave * 128 + s * 64) * 8]);
        }
        __syncthreads();
        frag a[4], b[4];
#pragma unroll
        for (int mt = 0; mt < 4; ++mt)
            a[mt] = *(const frag*)&As[(wm * 64 + mt * 16 + l16) * 32 + quad * 8];
#pragma unroll
        for (int nt = 0; nt < 4; ++nt)
            b[nt] = *(const frag*)&Ws[(wn * 64 + nt * 16 + l16) * 32 + quad * 8];
#pragma unroll
        for (int mt = 0; mt < 4; ++mt)
#pragma unroll
            for (int nt = 0; nt < 4; ++nt)
                acc[mt][nt] = __builtin_amdgcn_mfma_f32_16x16x32_bf16(
                    a[mt], b[nt], acc[mt][nt], 0, 0, 0);
        __syncthreads();
    }

    float bv[4];
#pragma unroll
    for (int nt = 0; nt < 4; ++nt)
        bv[nt] = bias[col0 + wn * 64 + nt * 16 + l16];
#pragma unroll
    for (int mt = 0; mt < 4; ++mt) {
#pragma unroll
        for (int nt = 0; nt < 4; ++nt) {
#pragma unroll
            for (int r = 0; r < 4; ++r) {
                int row = row0 + wm * 64 + mt * 16 + quad * 4 + r;   // = t*64+b
                int col = col0 + wn * 64 + nt * 16 + l16;
                int t = row >> 6, bb = row & 63;
                feats[((size_t)bb * TT + t) * VV + col] =
                    __float2bfloat16(acc[mt][nt][r] + bv[nt]);
            }
        }
    }
}

// ------ i-split scan: 1 chain/block, f16 dot2 matvec, 1-wave reduce+publish --
__global__ __launch_bounds__(512, 2)
void k_scan(const float* __restrict__ ETg,
            const __hip_bfloat16* __restrict__ feats,
            const int* __restrict__ lengths,
            unsigned long long* __restrict__ pay,
            float* __restrict__ out) {
    __shared__ unsigned int spf[16 * 17];   // p f16-pairs: row js, 16 pairs, pad 17
    __shared__ float spart[16 * CI];        // 16 js-partials x 128 i
    __shared__ float sm[NK];
    __shared__ float sfin[4];

    int tid = threadIdx.x;
    int b   = blockIdx.x & 63;       // peers {b, b+64, b+128, b+192} same XCD (%8)
    int kc  = blockIdx.x >> 6;       // i-chunk 0..3
    int lane = tid & 63, wid = tid >> 6;
    int len = lengths[b];
    int js = tid >> 5;               // j-slice 0..15 (32 j each)
    int ig = tid & 31;
    int i0 = ig * 4;                 // 4 i's per thread

#define PSLOT(s, c) (pay + ((size_t)(b) * 2 * NK + (size_t)(s) * NK + (c)) * PSTRIDE)

    // ---- eta: rows j=js*32..+32, cols kc*128+i0..+4, packed f16 j-pairs ----
    unsigned int eta[64];
    {
        const float* base = ETg + (size_t)(js * 32) * VV + kc * CI + i0;
#pragma unroll
        for (int jj = 0; jj < 16; ++jj) {
            float4 e0 = *(const float4*)(base + (size_t)(2 * jj) * VV);
            float4 e1 = *(const float4*)(base + (size_t)(2 * jj + 1) * VV);
            eta[jj * 4 + 0] = (unsigned int)f16b(e0.x) | ((unsigned int)f16b(e1.x) << 16);
            eta[jj * 4 + 1] = (unsigned int)f16b(e0.y) | ((unsigned int)f16b(e1.y) << 16);
            eta[jj * 4 + 2] = (unsigned int)f16b(e0.z) | ((unsigned int)f16b(e1.z) << 16);
            eta[jj * 4 + 3] = (unsigned int)f16b(e0.w) | ((unsigned int)f16b(e1.w) << 16);
        }
    }

    // ---- init publish: round 1 -> slot 1 (one wave; states 2*tid, 2*tid+1) --
    if (tid < 64) {
        float cm0 = (kc == 0) ? 0.f : NEGV;
        int g0 = kc * CI + 2 * tid, g1 = g0 + 1;
        float z0 = (g0 == BOSI) ? 0.f : NEGV;
        float z1 = (g1 == BOSI) ? 0.f : NEGV;
        unsigned short cmb = __bfloat16_as_ushort(__float2bfloat16(cm0));
        float cmu = __uint_as_float((unsigned int)cmb << 16);
        unsigned long long v = (1ull << 48) | ((unsigned long long)cmb << 32) |
                               ((unsigned long long)f16b(expf(z1 - cmu)) << 16) |
                               (unsigned long long)f16b(expf(z0 - cmu));
        __hip_atomic_store(&PSLOT(1, kc)[tid], v, __ATOMIC_RELAXED, __HIP_MEMORY_SCOPE_AGENT);
    }

    const __hip_bfloat16* fb = feats + (size_t)b * TT * VV;

    for (int t = 0; t < len; ++t) {
        // feats pair prefetch (reduce wave only; overlaps poll)
        float ft0 = 0.f, ft1 = 0.f;
        if (tid < 64) {
            unsigned int fp = *(const unsigned int*)(fb + (size_t)t * VV + kc * CI + 2 * tid);
            ft0 = __uint_as_float(fp << 16);
            ft1 = __uint_as_float(fp & 0xFFFF0000u);
        }

        // ---- poll: waves 4-7 (idle otherwise), 1 word each, self-validating --
        if (tid >= 256) {
            int pt = tid - 256;
            int pc = pt >> 6, pw = pt & 63;
            const unsigned long long* wp = &PSLOT((t + 1) & 1, pc)[pw];
            unsigned tgt = (unsigned)(t + 1);
            unsigned long long v;
            do {
                v = __hip_atomic_load(wp, __ATOMIC_RELAXED, __HIP_MEMORY_SCOPE_AGENT);
            } while ((unsigned)(v >> 48) < tgt);
            spf[(pc * 4 + (pw >> 4)) * 17 + (pw & 15)] = (unsigned int)v;
            if (pw == 0)
                sm[pc] = __uint_as_float(((unsigned int)(v >> 32) & 0xFFFFu) << 16);
        }
        __syncthreads();   // B1: spf + sm ready

        float M = fmaxf(fmaxf(sm[0], sm[1]), fmaxf(sm[2], sm[3]));
        float wloc = expf(sm[js >> 2] - M);

        // ---- matvec: f16 dot2 from registers ----
        float a0 = 0.f, a1 = 0.f, a2 = 0.f, a3 = 0.f;
#pragma unroll
        for (int jj = 0; jj < 16; ++jj) {
            unsigned int pp = spf[js * 17 + jj];
#if __has_builtin(__builtin_amdgcn_fdot2)
            h2 hp; __builtin_memcpy(&hp, &pp, 4);
            h2 e0, e1, e2, e3;
            __builtin_memcpy(&e0, &eta[jj * 4 + 0], 4);
            __builtin_memcpy(&e1, &eta[jj * 4 + 1], 4);
            __builtin_memcpy(&e2, &eta[jj * 4 + 2], 4);
            __builtin_memcpy(&e3, &eta[jj * 4 + 3], 4);
            a0 = __builtin_amdgcn_fdot2(e0, hp, a0, false);
            a1 = __builtin_amdgcn_fdot2(e1, hp, a1, false);
            a2 = __builtin_amdgcn_fdot2(e2, hp, a2, false);
            a3 = __builtin_amdgcn_fdot2(e3, hp, a3, false);
#else
            float p0 = f16f(pp), p1 = f16f(pp >> 16);
#pragma unroll
            for (int ii = 0; ii < 4; ++ii) {
                unsigned int e = eta[jj * 4 + ii];
                float v0 = f16f(e), v1 = f16f(e >> 16);
                float* ac = (ii == 0) ? &a0 : (ii == 1) ? &a1 : (ii == 2) ? &a2 : &a3;
                *ac = fmaf(v0, p0, fmaf(v1, p1, *ac));
            }
#endif
        }
        *(float4*)&spart[js * CI + i0] = make_float4(a0 * wloc, a1 * wloc, a2 * wloc, a3 * wloc);
        __syncthreads();   // B2: spart ready

        // ---- wave-0: reduce 16 partials, zn pair, in-wave chunk max, publish
        if (tid < 64) {
            float s0 = 0.f, s1 = 0.f;
#pragma unroll
            for (int q = 0; q < 16; ++q) {
                float2 v = *(const float2*)&spart[q * CI + 2 * tid];
                s0 += v.x; s1 += v.y;
            }
            float zn0 = M + logf(s0) + ft0;
            float zn1 = M + logf(s1) + ft1;
            float cm = fmaxf(zn0, zn1);
#pragma unroll
            for (int off = 32; off > 0; off >>= 1)
                cm = fmaxf(cm, __shfl_xor(cm, off, 64));
            unsigned short cmb = __bfloat16_as_ushort(__float2bfloat16(cm));
            float cmu = __uint_as_float((unsigned int)cmb << 16);
            unsigned long long v = ((unsigned long long)(unsigned)(t + 2) << 48) |
                                   ((unsigned long long)cmb << 32) |
                                   ((unsigned long long)f16b(expf(zn1 - cmu)) << 16) |
                                   (unsigned long long)f16b(expf(zn0 - cmu));
            __hip_atomic_store(&PSLOT(t & 1, kc)[tid], v, __ATOMIC_RELAXED, __HIP_MEMORY_SCOPE_AGENT);
        }
        // no third barrier: spf/sm rewritten only after B2 of this step (safe);
        // spart rewritten only after next B1, which wave 0 reaches post-publish.
    }

    // ---- final LSE over all 512 states (kc==0 block only) ----
    if (kc == 0) {
        if (tid >= 256) {
            int pt = tid - 256;
            int pc = pt >> 6, pw = pt & 63;
            const unsigned long long* wp = &PSLOT((len + 1) & 1, pc)[pw];
            unsigned tgt = (unsigned)(len + 1);
            unsigned long long v;
            do {
                v = __hip_atomic_load(wp, __ATOMIC_RELAXED, __HIP_MEMORY_SCOPE_AGENT);
            } while ((unsigned)(v >> 48) < tgt);
            spf[(pc * 4 + (pw >> 4)) * 17 + (pw & 15)] = (unsigned int)v;
            if (pw == 0)
                sm[pc] = __uint_as_float(((unsigned int)(v >> 32) & 0xFFFFu) << 16);
        }
        __syncthreads();
        float M = fmaxf(fmaxf(sm[0], sm[1]), fmaxf(sm[2], sm[3]));
        float s = 0.f;
        if (tid < 256) {
            int j0 = 2 * tid;
            unsigned int pp = spf[(j0 >> 5) * 17 + ((j0 & 31) >> 1)];
            s = (f16f(pp) + f16f(pp >> 16)) * expf(sm[tid >> 6] - M);
        }
#pragma unroll
        for (int off = 32; off > 0; off >>= 1)
            s += __shfl_xor(s, off, 64);
        if (lane == 0 && tid < 256) sfin[wid] = s;
        __syncthreads();
        if (tid == 0)
            out[b] = M + logf(sfin[0] + sfin[1] + sfin[2] + sfin[3]);
    }
#undef PSLOT
}

extern "C" void kernel_launch(void* const* d_in, const int* in_sizes, int n_in,
                              void* d_out, int out_size, void* d_ws, size_t ws_size,
                              hipStream_t stream) {
    const float* enc     = (const float*)d_in[0];  // [T,B,H]
    const int*   lengths = (const int*)d_in[1];    // [B]
    const float* W       = (const float*)d_in[2];  // [V,H]
    const float* bias    = (const float*)d_in[3];  // [V]
    const float* trans   = (const float*)d_in[4];  // [V,V]
    float* out = (float*)d_out;

    char* ws = (char*)d_ws;
    float*          ETg   = (float*)ws;
    __hip_bfloat16* feats = (__hip_bfloat16*)(ws + (1 << 20));
    unsigned long long* pay = (unsigned long long*)(ws + (17 << 20));
    __hip_bfloat16* Abf   = (__hip_bfloat16*)(ws + (18 << 20));
    __hip_bfloat16* Wbf   = (__hip_bfloat16*)(ws + (50 << 20));

    hipLaunchKernelGGL(k_zero, dim3(128), dim3(256), 0, stream, pay);
    hipLaunchKernelGGL(k_expT, dim3(16, 16), dim3(256), 0, stream, trans, ETg);
    hipLaunchKernelGGL(k_cast, dim3(16384), dim3(256), 0, stream, enc, Abf);
    hipLaunchKernelGGL(k_cast, dim3(512), dim3(256), 0, stream, W, Wbf);
    hipLaunchKernelGGL(k_feats, dim3(16384 / 128, VV / 128), dim3(256), 0, stream,
                       Abf, Wbf, bias, feats);
    hipLaunchKernelGGL(k_scan, dim3(NK * BB), dim3(512), 0, stream,
                       ETg, feats, lengths, pay, out);
}